// Round 14
// baseline (958.191 us; speedup 1.0000x reference)
//
#include <hip/hip_runtime.h>
#include <hip/hip_bf16.h>

#define NG 4
#define ID 128
#define HD 128
#define TH 384      // 3*HD
#define NB 32
#define NT 1000
#define XW (NG*ID)  // 512
#define OW (NG*HD)  // 512
// gi_ws layout, f16 units, per (b,g) region of NT*384:
//   t*384 + j*2     : r-gate (lo) | t*384 + j*2+1 : z-gate (hi)  (u32 pair)
//   t*384 + 256 + j : n-gate
// total 128 regions * 768KB = 98.304 MB.

typedef _Float16 v8h __attribute__((ext_vector_type(8)));
typedef __attribute__((ext_vector_type(4))) float v4f;

__device__ __forceinline__ float sigm(float v) {
    return __fdividef(1.f, 1.f + __expf(-v));
}
__device__ __forceinline__ float tanh_(float v) {
    v = fminf(fmaxf(v, -15.f), 15.f);
    float e2 = __expf(2.f * v);
    return __fdividef(e2 - 1.f, e2 + 1.f);
}
__device__ __forceinline__ float sel4(v4f a, int s) {
    float x01 = (s & 1) ? a[1] : a[0];
    float x23 = (s & 1) ? a[3] : a[2];
    return (s & 2) ? x23 : x01;
}

// ---------------- Phase 1 (R10-proven, unchanged): gi = x @ w_ih^T + b_ih.
// grid (3, 256, 4) [gate, b*8+ttile, g], block 256.
__global__ __launch_bounds__(256) void gi_gemm4(
    const float* __restrict__ x,
    const float* __restrict__ w_ih,
    const float* __restrict__ b_ih,
    _Float16* __restrict__ gi_ws)
{
    const int tid = threadIdx.x;
    const int w   = tid >> 6, l = tid & 63;
    const int lr  = l & 15, lq = l >> 4;
    const int g   = blockIdx.z;
    const int b   = blockIdx.y >> 3;
    const int tt  = blockIdx.y & 7;
    const int gate = blockIdx.x;
    const int n0  = gate * 128 + (w >> 1) * 64;
    const int t0  = tt * 128 + (w & 1) * 64;

    v4f acc[4][4];
    #pragma unroll
    for (int mi = 0; mi < 4; ++mi)
        #pragma unroll
        for (int ni = 0; ni < 4; ++ni)
            acc[mi][ni] = (v4f){0.f, 0.f, 0.f, 0.f};

    #pragma unroll
    for (int kf = 0; kf < 4; ++kf) {
        v8h bf[4], af[4];
        #pragma unroll
        for (int ni = 0; ni < 4; ++ni) {
            const float* p = &w_ih[(size_t)(g * TH + n0 + ni * 16 + lr) * ID + kf * 32 + lq * 8];
            float4 f0 = *reinterpret_cast<const float4*>(p);
            float4 f1 = *reinterpret_cast<const float4*>(p + 4);
            v8h v;
            v[0]=(_Float16)f0.x; v[1]=(_Float16)f0.y; v[2]=(_Float16)f0.z; v[3]=(_Float16)f0.w;
            v[4]=(_Float16)f1.x; v[5]=(_Float16)f1.y; v[6]=(_Float16)f1.z; v[7]=(_Float16)f1.w;
            bf[ni] = v;
        }
        #pragma unroll
        for (int mi = 0; mi < 4; ++mi) {
            int trow = t0 + mi * 16 + lr;
            int tl = trow < NT ? trow : NT - 1;
            const float* p = &x[((size_t)b * NT + tl) * XW + g * ID + kf * 32 + lq * 8];
            float4 f0 = *reinterpret_cast<const float4*>(p);
            float4 f1 = *reinterpret_cast<const float4*>(p + 4);
            v8h v;
            v[0]=(_Float16)f0.x; v[1]=(_Float16)f0.y; v[2]=(_Float16)f0.z; v[3]=(_Float16)f0.w;
            v[4]=(_Float16)f1.x; v[5]=(_Float16)f1.y; v[6]=(_Float16)f1.z; v[7]=(_Float16)f1.w;
            af[mi] = v;
        }
        #pragma unroll
        for (int mi = 0; mi < 4; ++mi)
            #pragma unroll
            for (int ni = 0; ni < 4; ++ni)
                acc[mi][ni] = __builtin_amdgcn_mfma_f32_16x16x32_f16(
                    af[mi], bf[ni], acc[mi][ni], 0, 0, 0);
    }

    const size_t rbase = (size_t)(b * NG + g) * NT;
    #pragma unroll
    for (int ni = 0; ni < 4; ++ni) {
        const int col = n0 + ni * 16 + lr;
        const float bias = b_ih[g * TH + col];
        const int jj = col & 127;
        const int off = (gate == 0) ? jj * 2 : (gate == 1) ? jj * 2 + 1 : 256 + jj;
        #pragma unroll
        for (int mi = 0; mi < 4; ++mi) {
            #pragma unroll
            for (int r = 0; r < 4; ++r) {
                const int t = t0 + mi * 16 + lq * 4 + r;
                if (t < NT)
                    gi_ws[(rbase + t) * 384 + off] = (_Float16)(acc[mi][ni][r] + bias);
            }
        }
    }
}

// ---------------- Phase 2: dual-sequence broadcast-B MFMA recurrence.
// grid 64 (g, batch-pair), block 512. Each step handles seq A and B:
// MFMA_B's pipe latency is filled by gates_A on the VALU (m114 overlap).
// R11-proven sync (raw s_barrier + lgkmcnt(0), vmcnt never drained in-loop),
// R11-proven per-step interleaved stores, 4-deep MFMA chains, 2-step prefetch.
__global__ __launch_bounds__(512) void gru_recC(
    const _Float16* __restrict__ gi_ws,
    const float* __restrict__ w_hh,
    const float* __restrict__ b_hh,
    float* __restrict__ out)
{
    __shared__ __align__(16) _Float16 h_lds[2][2][128];   // [parity][seq][j]

    const int tid = threadIdx.x;
    const int w = tid >> 6, l = tid & 63;
    const int lr = l & 15, lq = l >> 4;
    const int g  = blockIdx.x & 3;
    const int bp = blockIdx.x >> 2;          // 0..15
    const int bA = bp * 2, bB = bp * 2 + 1;

    // ---- w_hh A-frags (R10-proven; shared by both sequences)
    v8h a[3][4];
    #pragma unroll
    for (int i = 0; i < 3; ++i) {
        const int mrow = i * 128 + 16 * w + lr;
        #pragma unroll
        for (int kf = 0; kf < 4; ++kf) {
            const float* p = &w_hh[(size_t)(g * TH + mrow) * HD + kf * 32 + lq * 8];
            float4 f0 = *reinterpret_cast<const float4*>(p);
            float4 f1 = *reinterpret_cast<const float4*>(p + 4);
            v8h v;
            v[0]=(_Float16)f0.x; v[1]=(_Float16)f0.y; v[2]=(_Float16)f0.z; v[3]=(_Float16)f0.w;
            v[4]=(_Float16)f1.x; v[5]=(_Float16)f1.y; v[6]=(_Float16)f1.z; v[7]=(_Float16)f1.w;
            a[i][kf] = v;
        }
    }

    // ---- gate identity (R10-proven): j = 16w + 4*lq + sel; 4 copies, 1 active
    const int sel = l & 3;
    const int j   = 16 * w + 4 * lq + sel;
    const bool active = ((l >> 2) & 3) == 0;
    const v4f bv0 = *reinterpret_cast<const v4f*>(&b_hh[g * TH +       16 * w + 4 * lq]);
    const v4f bv1 = *reinterpret_cast<const v4f*>(&b_hh[g * TH + 128 + 16 * w + 4 * lq]);
    const v4f bv2 = *reinterpret_cast<const v4f*>(&b_hh[g * TH + 256 + 16 * w + 4 * lq]);
    float hprevA = 0.f, hprevB = 0.f;
    float* outA = out + (size_t)bA * NT * OW + g * HD + j;
    float* outB = out + (size_t)bB * NT * OW + g * HD + j;

    if (tid < 256) reinterpret_cast<unsigned int*>(h_lds)[tid] = 0u;

    const char* gsrcA = reinterpret_cast<const char*>(
        gi_ws + (size_t)(bA * NG + g) * NT * 384);
    const char* gsrcB = reinterpret_cast<const char*>(
        gi_ws + (size_t)(bB * NG + g) * NT * 384);
    const int off_rz = j * 4;            // byte offset of (r,z) u32
    const int off_nv = 512 + j * 2;      // byte offset of n u16

    // ---- gi reg-ring, 2-step lead, per seq per parity
    unsigned int rzA0, rzA1, rzB0, rzB1;
    _Float16 nvA0, nvA1, nvB0, nvB1;
    rzA0 = *reinterpret_cast<const unsigned int*>(gsrcA + off_rz);
    nvA0 = *reinterpret_cast<const _Float16*>(gsrcA + off_nv);
    rzA1 = *reinterpret_cast<const unsigned int*>(gsrcA + 768 + off_rz);
    nvA1 = *reinterpret_cast<const _Float16*>(gsrcA + 768 + off_nv);
    rzB0 = *reinterpret_cast<const unsigned int*>(gsrcB + off_rz);
    nvB0 = *reinterpret_cast<const _Float16*>(gsrcB + off_nv);
    rzB1 = *reinterpret_cast<const unsigned int*>(gsrcB + 768 + off_rz);
    nvB1 = *reinterpret_cast<const _Float16*>(gsrcB + 768 + off_nv);
    const char* pA0 = gsrcA + 2 * 768;   // A even-parity prefetch base (t+2)
    const char* pA1 = gsrcA + 3 * 768;   // A odd
    const char* pB0 = gsrcB + 2 * 768;
    const char* pB1 = gsrcB + 3 * 768;
    __syncthreads();   // once; drains prologue loads + LDS zero-init

#define MM(AC, I, K, F) AC = __builtin_amdgcn_mfma_f32_16x16x32_f16(a[I][K], F, AC, 0, 0, 0)

#define GATES(AC0, AC1, AC2, RZ, NV, HPREV, HLDS, OUTP)                            \
    {                                                                              \
        float ghr = sel4(AC0, sel);                                                \
        float ghz = sel4(AC1, sel);                                                \
        float ghn = sel4(AC2, sel);                                                \
        float iR = (float)__builtin_bit_cast(_Float16, (unsigned short)(RZ & 0xffff)); \
        float iZ = (float)__builtin_bit_cast(_Float16, (unsigned short)(RZ >> 16));    \
        float iN = (float)NV;                                                      \
        float rr = sigm(iR + ghr);                                                 \
        float zz = sigm(iZ + ghz);                                                 \
        float nn = tanh_(fmaf(rr, ghn, iN));                                       \
        float hn = fmaf(zz, HPREV - nn, nn);                                       \
        HPREV = hn;                                                                \
        if (active) { HLDS[j] = (_Float16)hn; *OUTP = hn; }                        \
        OUTP += OW;                                                                \
    }

#define STEP(P, RZA, NVA, RZB, NVB, PA, PB, DO_PF)                                 \
    {                                                                              \
        const char* hbA = reinterpret_cast<const char*>(&h_lds[P][0][0]) + lq * 16;\
        const char* hbB = reinterpret_cast<const char*>(&h_lds[P][1][0]) + lq * 16;\
        v8h fA0 = *reinterpret_cast<const v8h*>(hbA);                              \
        v8h fA1 = *reinterpret_cast<const v8h*>(hbA + 64);                         \
        v8h fA2 = *reinterpret_cast<const v8h*>(hbA + 128);                        \
        v8h fA3 = *reinterpret_cast<const v8h*>(hbA + 192);                        \
        v8h fB0 = *reinterpret_cast<const v8h*>(hbB);                              \
        v8h fB1 = *reinterpret_cast<const v8h*>(hbB + 64);                         \
        v8h fB2 = *reinterpret_cast<const v8h*>(hbB + 128);                        \
        v8h fB3 = *reinterpret_cast<const v8h*>(hbB + 192);                        \
        v4f aA0 = bv0, aA1 = bv1, aA2 = bv2;                                       \
        MM(aA0, 0, 0, fA0); MM(aA1, 1, 0, fA0); MM(aA2, 2, 0, fA0);                \
        MM(aA0, 0, 1, fA1); MM(aA1, 1, 1, fA1); MM(aA2, 2, 1, fA1);                \
        MM(aA0, 0, 2, fA2); MM(aA1, 1, 2, fA2); MM(aA2, 2, 2, fA2);                \
        MM(aA0, 0, 3, fA3); MM(aA1, 1, 3, fA3); MM(aA2, 2, 3, fA3);                \
        v4f aB0 = bv0, aB1 = bv1, aB2 = bv2;                                       \
        MM(aB0, 0, 0, fB0); MM(aB1, 1, 0, fB0); MM(aB2, 2, 0, fB0);                \
        MM(aB0, 0, 1, fB1); MM(aB1, 1, 1, fB1); MM(aB2, 2, 1, fB1);                \
        MM(aB0, 0, 2, fB2); MM(aB1, 1, 2, fB2); MM(aB2, 2, 2, fB2);                \
        MM(aB0, 0, 3, fB3); MM(aB1, 1, 3, fB3); MM(aB2, 2, 3, fB3);                \
        GATES(aA0, aA1, aA2, RZA, NVA, hprevA, h_lds[(P) ^ 1][0], outA)            \
        GATES(aB0, aB1, aB2, RZB, NVB, hprevB, h_lds[(P) ^ 1][1], outB)            \
        if (DO_PF) {                                                               \
            RZA = *reinterpret_cast<const unsigned int*>(PA + off_rz);             \
            NVA = *reinterpret_cast<const _Float16*>(PA + off_nv);                 \
            PA += 1536;                                                            \
            RZB = *reinterpret_cast<const unsigned int*>(PB + off_rz);             \
            NVB = *reinterpret_cast<const _Float16*>(PB + off_nv);                 \
            PB += 1536;                                                            \
        }                                                                          \
        asm volatile("s_waitcnt lgkmcnt(0)" ::: "memory");                         \
        __builtin_amdgcn_s_barrier();                                              \
        __builtin_amdgcn_sched_barrier(0);                                         \
    }

    for (int t = 0; t < NT - 2; t += 2) {
        STEP(0, rzA0, nvA0, rzB0, nvB0, pA0, pB0, 1)
        STEP(1, rzA1, nvA1, rzB1, nvB1, pA1, pB1, 1)
    }
    // epilogue t = 998, 999 (no prefetch)
    STEP(0, rzA0, nvA0, rzB0, nvB0, pA0, pB0, 0)
    STEP(1, rzA1, nvA1, rzB1, nvB1, pA1, pB1, 0)
#undef STEP
#undef GATES
#undef MM
}

extern "C" void kernel_launch(void* const* d_in, const int* in_sizes, int n_in,
                              void* d_out, int out_size, void* d_ws, size_t ws_size,
                              hipStream_t stream) {
    const float* x    = (const float*)d_in[0];
    const float* w_ih = (const float*)d_in[1];
    const float* w_hh = (const float*)d_in[2];
    const float* b_ih = (const float*)d_in[3];
    const float* b_hh = (const float*)d_in[4];
    float* out = (float*)d_out;
    _Float16* gi_ws = (_Float16*)d_ws;   // 98.304 MB, layout above

    dim3 g1(3, NB * 8, NG);
    gi_gemm4<<<g1, 256, 0, stream>>>(x, w_ih, b_ih, gi_ws);
    gru_recC<<<64, 512, 0, stream>>>(gi_ws, w_hh, b_hh, out);
}

// Round 15
// 633.351 us; speedup vs baseline: 1.5129x; 1.5129x over previous
//
#include <hip/hip_runtime.h>
#include <hip/hip_bf16.h>

#define NG 4
#define ID 128
#define HD 128
#define TH 384      // 3*HD
#define NB 32
#define NT 1000
#define XW (NG*ID)  // 512
#define OW (NG*HD)  // 512

typedef _Float16 v8h __attribute__((ext_vector_type(8)));
typedef __attribute__((ext_vector_type(4))) float v4f;

__device__ __forceinline__ float sigm(float v) {
    return __fdividef(1.f, 1.f + __expf(-v));
}
__device__ __forceinline__ float tanh_(float v) {
    v = fminf(fmaxf(v, -15.f), 15.f);
    float e2 = __expf(2.f * v);
    return __fdividef(e2 - 1.f, e2 + 1.f);
}
__device__ __forceinline__ float sel4(v4f a, int s) {
    float x01 = (s & 1) ? a[1] : a[0];
    float x23 = (s & 1) ? a[3] : a[2];
    return (s & 2) ? x23 : x01;
}

// ---------------- Pre-pass: x f32 -> f16, relaid as [b,g][t][128] (256B rows).
// grid (32, 1000), block 128.
__global__ __launch_bounds__(128) void x_cvt(
    const float* __restrict__ x, _Float16* __restrict__ x16)
{
    const int b = blockIdx.x, t = blockIdx.y;
    const int tid = threadIdx.x;
    const int g = tid >> 5, cc = (tid & 31) * 4;
    float4 v = *reinterpret_cast<const float4*>(
        &x[((size_t)b * NT + t) * XW + g * ID + cc]);
    union { _Float16 h[4]; uint2 u; } pk;
    pk.h[0] = (_Float16)v.x; pk.h[1] = (_Float16)v.y;
    pk.h[2] = (_Float16)v.z; pk.h[3] = (_Float16)v.w;
    *reinterpret_cast<uint2*>(
        &x16[(((size_t)b * NG + g) * NT + t) * ID + cc]) = pk.u;
}

// ---------------- Fused GRU: input projection AND recurrence per step.
// grid 128 (1 seq/WG), 8 waves. R11-proven sync/stores/gates/h ping-pong.
// i-accs = mfma(w_ih_frags, x_frags) issued during the h ds_read latency;
// x frags read direct from global (L2-resident), 2-step prefetch lead.
__global__ __launch_bounds__(512) void gru_recD(
    const _Float16* __restrict__ x16,
    const float* __restrict__ w_ih,
    const float* __restrict__ w_hh,
    const float* __restrict__ b_ih,
    const float* __restrict__ b_hh,
    float* __restrict__ out)
{
    __shared__ __align__(16) _Float16 h_lds[2][128];

    const int tid = threadIdx.x;
    const int w = tid >> 6, l = tid & 63;
    const int lr = l & 15, lq = l >> 4;
    const int g = blockIdx.x & 3;
    const int b = blockIdx.x >> 2;

    // ---- A-frags, once: aH from w_hh (R10-proven), aI from w_ih (same pattern)
    v8h aH[3][4], aI[3][4];
    #pragma unroll
    for (int i = 0; i < 3; ++i) {
        const int mrow = i * 128 + 16 * w + lr;
        #pragma unroll
        for (int kf = 0; kf < 4; ++kf) {
            const float* p = &w_hh[(size_t)(g * TH + mrow) * HD + kf * 32 + lq * 8];
            float4 f0 = *reinterpret_cast<const float4*>(p);
            float4 f1 = *reinterpret_cast<const float4*>(p + 4);
            v8h v;
            v[0]=(_Float16)f0.x; v[1]=(_Float16)f0.y; v[2]=(_Float16)f0.z; v[3]=(_Float16)f0.w;
            v[4]=(_Float16)f1.x; v[5]=(_Float16)f1.y; v[6]=(_Float16)f1.z; v[7]=(_Float16)f1.w;
            aH[i][kf] = v;
            const float* q = &w_ih[(size_t)(g * TH + mrow) * ID + kf * 32 + lq * 8];
            float4 g0 = *reinterpret_cast<const float4*>(q);
            float4 g1 = *reinterpret_cast<const float4*>(q + 4);
            v8h u;
            u[0]=(_Float16)g0.x; u[1]=(_Float16)g0.y; u[2]=(_Float16)g0.z; u[3]=(_Float16)g0.w;
            u[4]=(_Float16)g1.x; u[5]=(_Float16)g1.y; u[6]=(_Float16)g1.z; u[7]=(_Float16)g1.w;
            aI[i][kf] = u;
        }
    }

    // ---- gate identity (R10-proven): j = 16w + 4*lq + sel; 4 copies, 1 active
    const int sel = l & 3;
    const int j   = 16 * w + 4 * lq + sel;
    const bool active = ((l >> 2) & 3) == 0;
    const v4f bh0 = *reinterpret_cast<const v4f*>(&b_hh[g * TH +       16 * w + 4 * lq]);
    const v4f bh1 = *reinterpret_cast<const v4f*>(&b_hh[g * TH + 128 + 16 * w + 4 * lq]);
    const v4f bh2 = *reinterpret_cast<const v4f*>(&b_hh[g * TH + 256 + 16 * w + 4 * lq]);
    const v4f bi0 = *reinterpret_cast<const v4f*>(&b_ih[g * TH +       16 * w + 4 * lq]);
    const v4f bi1 = *reinterpret_cast<const v4f*>(&b_ih[g * TH + 128 + 16 * w + 4 * lq]);
    const v4f bi2 = *reinterpret_cast<const v4f*>(&b_ih[g * TH + 256 + 16 * w + 4 * lq]);
    float hprev = 0.f;
    float* outp = out + (size_t)b * NT * OW + g * HD + j;

    if (tid < 128) { h_lds[0][tid] = (_Float16)0.f; h_lds[1][tid] = (_Float16)0.f; }

    // ---- x frags: broadcast within 16-lane groups (lq-dependent addr only);
    // one 256B row per t. Current frags for t (parity) + prefetch into same regs.
    const char* xbase = reinterpret_cast<const char*>(
        x16 + ((size_t)(b * NG + g)) * NT * ID);
    const int fo = lq * 16;
    v8h xe0, xe1, xe2, xe3, xo0, xo1, xo2, xo3;
    xe0 = *reinterpret_cast<const v8h*>(xbase +   0 + fo);
    xe1 = *reinterpret_cast<const v8h*>(xbase +  64 + fo);
    xe2 = *reinterpret_cast<const v8h*>(xbase + 128 + fo);
    xe3 = *reinterpret_cast<const v8h*>(xbase + 192 + fo);
    xo0 = *reinterpret_cast<const v8h*>(xbase + 256 + fo);
    xo1 = *reinterpret_cast<const v8h*>(xbase + 320 + fo);
    xo2 = *reinterpret_cast<const v8h*>(xbase + 384 + fo);
    xo3 = *reinterpret_cast<const v8h*>(xbase + 448 + fo);
    const char* pxE = xbase + 2 * 256;   // even-parity prefetch base (t+2)
    const char* pxO = xbase + 3 * 256;
    __syncthreads();   // once; drains prologue loads + LDS zero-init

#define MM(AC, AF, K, F) AC = __builtin_amdgcn_mfma_f32_16x16x32_f16(AF[K], F, AC, 0, 0, 0)

#define STEP(P, X0, X1, X2, X3, PX, DO_PF)                                         \
    {                                                                              \
        const char* hb = reinterpret_cast<const char*>(&h_lds[P][0]) + fo;         \
        v8h f0 = *reinterpret_cast<const v8h*>(hb);                                \
        v8h f1 = *reinterpret_cast<const v8h*>(hb + 64);                           \
        v8h f2 = *reinterpret_cast<const v8h*>(hb + 128);                          \
        v8h f3 = *reinterpret_cast<const v8h*>(hb + 192);                          \
        /* i-MFMAs first: x frags are long-ready; fills h ds_read latency */       \
        v4f i0 = bi0, i1 = bi1, i2 = bi2;                                          \
        MM(i0, aI[0], 0, X0); MM(i1, aI[1], 0, X0); MM(i2, aI[2], 0, X0);          \
        MM(i0, aI[0], 1, X1); MM(i1, aI[1], 1, X1); MM(i2, aI[2], 1, X1);          \
        MM(i0, aI[0], 2, X2); MM(i1, aI[1], 2, X2); MM(i2, aI[2], 2, X2);          \
        MM(i0, aI[0], 3, X3); MM(i1, aI[1], 3, X3); MM(i2, aI[2], 3, X3);          \
        v4f c0 = bh0, c1 = bh1, c2 = bh2;                                          \
        MM(c0, aH[0], 0, f0); MM(c1, aH[1], 0, f0); MM(c2, aH[2], 0, f0);          \
        MM(c0, aH[0], 1, f1); MM(c1, aH[1], 1, f1); MM(c2, aH[2], 1, f1);          \
        MM(c0, aH[0], 2, f2); MM(c1, aH[1], 2, f2); MM(c2, aH[2], 2, f2);          \
        MM(c0, aH[0], 3, f3); MM(c1, aH[1], 3, f3); MM(c2, aH[2], 3, f3);          \
        float iR = sel4(i0, sel);                                                  \
        float iZ = sel4(i1, sel);                                                  \
        float iN = sel4(i2, sel);                                                  \
        float ghr = sel4(c0, sel);                                                 \
        float ghz = sel4(c1, sel);                                                 \
        float ghn = sel4(c2, sel);                                                 \
        float rr = sigm(iR + ghr);                                                 \
        float zz = sigm(iZ + ghz);                                                 \
        float nn = tanh_(fmaf(rr, ghn, iN));                                       \
        float hn = fmaf(zz, hprev - nn, nn);                                       \
        hprev = hn;                                                                \
        if (active) {                                                              \
            h_lds[(P) ^ 1][j] = (_Float16)hn;                                      \
            *outp = hn;                                                            \
        }                                                                          \
        outp += OW;                                                                \
        if (DO_PF) {                                                               \
            X0 = *reinterpret_cast<const v8h*>(PX +   0 + fo);                     \
            X1 = *reinterpret_cast<const v8h*>(PX +  64 + fo);                     \
            X2 = *reinterpret_cast<const v8h*>(PX + 128 + fo);                     \
            X3 = *reinterpret_cast<const v8h*>(PX + 192 + fo);                     \
            PX += 512;                                                             \
        }                                                                          \
        asm volatile("s_waitcnt lgkmcnt(0)" ::: "memory");                         \
        __builtin_amdgcn_s_barrier();                                              \
        __builtin_amdgcn_sched_barrier(0);                                         \
    }

    for (int t = 0; t < NT - 2; t += 2) {
        STEP(0, xe0, xe1, xe2, xe3, pxE, 1)
        STEP(1, xo0, xo1, xo2, xo3, pxO, 1)
    }
    // epilogue t = 998, 999 (no prefetch)
    STEP(0, xe0, xe1, xe2, xe3, pxE, 0)
    STEP(1, xo0, xo1, xo2, xo3, pxO, 0)
#undef STEP
#undef MM
}

extern "C" void kernel_launch(void* const* d_in, const int* in_sizes, int n_in,
                              void* d_out, int out_size, void* d_ws, size_t ws_size,
                              hipStream_t stream) {
    const float* x    = (const float*)d_in[0];
    const float* w_ih = (const float*)d_in[1];
    const float* w_hh = (const float*)d_in[2];
    const float* b_ih = (const float*)d_in[3];
    const float* b_hh = (const float*)d_in[4];
    float* out = (float*)d_out;
    _Float16* x16 = (_Float16*)d_ws;   // [b,g][t][128] f16 = 32.8 MB

    dim3 gc(NB, NT);
    x_cvt<<<gc, 128, 0, stream>>>(x, x16);
    gru_recD<<<NB * NG, 512, 0, stream>>>(x16, w_ih, w_hh, b_ih, b_hh, out);
}

// Round 16
// 544.259 us; speedup vs baseline: 1.7605x; 1.1637x over previous
//
#include <hip/hip_runtime.h>
#include <hip/hip_bf16.h>

#define NG 4
#define ID 128
#define HD 128
#define TH 384      // 3*HD
#define NB 32
#define NT 1000
#define XW (NG*ID)  // 512
#define OW (NG*HD)  // 512
// gi_ws layout, f16 units, per (b,g) region of NT*384:
//   t*384 + j*2     : r-gate (lo) | t*384 + j*2+1 : z-gate (hi)  (u32 pair)
//   t*384 + 256 + j : n-gate
// total 128 regions * 768KB = 98.304 MB.

typedef _Float16 v8h __attribute__((ext_vector_type(8)));
typedef __attribute__((ext_vector_type(4))) float v4f;

__device__ __forceinline__ float sigm(float v) {
    return __fdividef(1.f, 1.f + __expf(-v));
}
__device__ __forceinline__ float tanh_(float v) {
    v = fminf(fmaxf(v, -15.f), 15.f);
    float e2 = __expf(2.f * v);
    return __fdividef(e2 - 1.f, e2 + 1.f);
}
__device__ __forceinline__ float sel4(v4f a, int s) {
    float x01 = (s & 1) ? a[1] : a[0];
    float x23 = (s & 1) ? a[3] : a[2];
    return (s & 2) ? x23 : x01;
}

// ---------------- Phase 1 (R10-proven, unchanged): gi = x @ w_ih^T + b_ih.
// grid (3, 256, 4) [gate, b*8+ttile, g], block 256.
__global__ __launch_bounds__(256) void gi_gemm4(
    const float* __restrict__ x,
    const float* __restrict__ w_ih,
    const float* __restrict__ b_ih,
    _Float16* __restrict__ gi_ws)
{
    const int tid = threadIdx.x;
    const int w   = tid >> 6, l = tid & 63;
    const int lr  = l & 15, lq = l >> 4;
    const int g   = blockIdx.z;
    const int b   = blockIdx.y >> 3;
    const int tt  = blockIdx.y & 7;
    const int gate = blockIdx.x;
    const int n0  = gate * 128 + (w >> 1) * 64;
    const int t0  = tt * 128 + (w & 1) * 64;

    v4f acc[4][4];
    #pragma unroll
    for (int mi = 0; mi < 4; ++mi)
        #pragma unroll
        for (int ni = 0; ni < 4; ++ni)
            acc[mi][ni] = (v4f){0.f, 0.f, 0.f, 0.f};

    #pragma unroll
    for (int kf = 0; kf < 4; ++kf) {
        v8h bf[4], af[4];
        #pragma unroll
        for (int ni = 0; ni < 4; ++ni) {
            const float* p = &w_ih[(size_t)(g * TH + n0 + ni * 16 + lr) * ID + kf * 32 + lq * 8];
            float4 f0 = *reinterpret_cast<const float4*>(p);
            float4 f1 = *reinterpret_cast<const float4*>(p + 4);
            v8h v;
            v[0]=(_Float16)f0.x; v[1]=(_Float16)f0.y; v[2]=(_Float16)f0.z; v[3]=(_Float16)f0.w;
            v[4]=(_Float16)f1.x; v[5]=(_Float16)f1.y; v[6]=(_Float16)f1.z; v[7]=(_Float16)f1.w;
            bf[ni] = v;
        }
        #pragma unroll
        for (int mi = 0; mi < 4; ++mi) {
            int trow = t0 + mi * 16 + lr;
            int tl = trow < NT ? trow : NT - 1;
            const float* p = &x[((size_t)b * NT + tl) * XW + g * ID + kf * 32 + lq * 8];
            float4 f0 = *reinterpret_cast<const float4*>(p);
            float4 f1 = *reinterpret_cast<const float4*>(p + 4);
            v8h v;
            v[0]=(_Float16)f0.x; v[1]=(_Float16)f0.y; v[2]=(_Float16)f0.z; v[3]=(_Float16)f0.w;
            v[4]=(_Float16)f1.x; v[5]=(_Float16)f1.y; v[6]=(_Float16)f1.z; v[7]=(_Float16)f1.w;
            af[mi] = v;
        }
        #pragma unroll
        for (int mi = 0; mi < 4; ++mi)
            #pragma unroll
            for (int ni = 0; ni < 4; ++ni)
                acc[mi][ni] = __builtin_amdgcn_mfma_f32_16x16x32_f16(
                    af[mi], bf[ni], acc[mi][ni], 0, 0, 0);
    }

    const size_t rbase = (size_t)(b * NG + g) * NT;
    #pragma unroll
    for (int ni = 0; ni < 4; ++ni) {
        const int col = n0 + ni * 16 + lr;
        const float bias = b_ih[g * TH + col];
        const int jj = col & 127;
        const int off = (gate == 0) ? jj * 2 : (gate == 1) ? jj * 2 + 1 : 256 + jj;
        #pragma unroll
        for (int mi = 0; mi < 4; ++mi) {
            #pragma unroll
            for (int r = 0; r < 4; ++r) {
                const int t = t0 + mi * 16 + lq * 4 + r;
                if (t < NT)
                    gi_ws[(rbase + t) * 384 + off] = (_Float16)(acc[mi][ni][r] + bias);
            }
        }
    }
}

// ---------------- Phase 2: broadcast-B MFMA recurrence, 4 waves (256 thr),
// 1 wave/SIMD. Wave w: j in [32w,32w+32) via 2 m-tiles per gate (24 MFMAs).
// Gate redundancy 2x (was 4x); broadcast ds_reads and barrier width halved.
// R11-proven sync (raw s_barrier + lgkmcnt(0); vmcnt never drained in-loop),
// per-step interleaved stores, gi 2-step reg prefetch, h ping-pong.
__global__ __launch_bounds__(256) void gru_recE(
    const _Float16* __restrict__ gi_ws,
    const float* __restrict__ w_hh,
    const float* __restrict__ b_hh,
    float* __restrict__ out)
{
    __shared__ __align__(16) _Float16 h_lds[2][128];

    const int tid = threadIdx.x;
    const int w = tid >> 6, l = tid & 63;
    const int lr = l & 15, lq = l >> 4;
    const int g = blockIdx.x & 3;
    const int b = blockIdx.x >> 2;

    // ---- w_hh A-frags: a[gate][t2][kf], rows gate*128 + 32w + 16*t2 + lr
    v8h a[3][2][4];
    #pragma unroll
    for (int i = 0; i < 3; ++i)
        #pragma unroll
        for (int t2 = 0; t2 < 2; ++t2) {
            const int mrow = i * 128 + 32 * w + 16 * t2 + lr;
            #pragma unroll
            for (int kf = 0; kf < 4; ++kf) {
                const float* p = &w_hh[(size_t)(g * TH + mrow) * HD + kf * 32 + lq * 8];
                float4 f0 = *reinterpret_cast<const float4*>(p);
                float4 f1 = *reinterpret_cast<const float4*>(p + 4);
                v8h v;
                v[0]=(_Float16)f0.x; v[1]=(_Float16)f0.y; v[2]=(_Float16)f0.z; v[3]=(_Float16)f0.w;
                v[4]=(_Float16)f1.x; v[5]=(_Float16)f1.y; v[6]=(_Float16)f1.z; v[7]=(_Float16)f1.w;
                a[i][t2][kf] = v;
            }
        }

    // ---- gate identity: sel = lr&3, t2s = (lr>>2)&1, j = 32w+16*t2s+4lq+sel.
    // lr and lr+8 give the same j => 2 redundant copies; active = lr<8.
    const int sel = lr & 3;
    const int t2s = (lr >> 2) & 1;
    const int j   = 32 * w + 16 * t2s + 4 * lq + sel;
    const bool active = (lr < 8);
    // biases as acc-init vectors per t2: reg r = b_hh[gate][32w+16t2+4lq+r]
    v4f bh[3][2];
    #pragma unroll
    for (int i = 0; i < 3; ++i)
        #pragma unroll
        for (int t2 = 0; t2 < 2; ++t2)
            bh[i][t2] = *reinterpret_cast<const v4f*>(
                &b_hh[g * TH + i * 128 + 32 * w + 16 * t2 + 4 * lq]);
    float hprev = 0.f;
    float* outp = out + (size_t)b * NT * OW + g * HD + j;

    if (tid < 128) { h_lds[0][tid] = (_Float16)0.f; h_lds[1][tid] = (_Float16)0.f; }

    const char* gsrc = reinterpret_cast<const char*>(
        gi_ws + (size_t)(b * NG + g) * NT * 384);
    const int off_rz = j * 4;            // byte offset of (r,z) u32
    const int off_nv = 512 + j * 2;      // byte offset of n u16

    // ---- gi reg-ring, 2-step lead (per parity)
    unsigned int rz0, rz1;
    _Float16 nv0, nv1;
    rz0 = *reinterpret_cast<const unsigned int*>(gsrc + off_rz);
    nv0 = *reinterpret_cast<const _Float16*>(gsrc + off_nv);
    rz1 = *reinterpret_cast<const unsigned int*>(gsrc + 768 + off_rz);
    nv1 = *reinterpret_cast<const _Float16*>(gsrc + 768 + off_nv);
    const char* pEb = gsrc + 2 * 768;    // even-parity prefetch base (t+2)
    const char* pOb = gsrc + 3 * 768;    // odd
    __syncthreads();   // once; drains prologue loads + LDS zero-init

#define MM(AC, I, T2, K, F) AC = __builtin_amdgcn_mfma_f32_16x16x32_f16(a[I][T2], F, AC, 0, 0, 0)[0*K+K-K] // placeholder
#undef MM
#define MM(AC, I, T2, K, F) AC = __builtin_amdgcn_mfma_f32_16x16x32_f16(a[I][T2][K], F, AC, 0, 0, 0)

#define STEP(P, RZ, NV, PPTR, DO_PF)                                               \
    {                                                                              \
        const char* hb = reinterpret_cast<const char*>(&h_lds[P][0]) + lq * 16;    \
        v8h f0 = *reinterpret_cast<const v8h*>(hb);                                \
        v8h f1 = *reinterpret_cast<const v8h*>(hb + 64);                           \
        v8h f2 = *reinterpret_cast<const v8h*>(hb + 128);                          \
        v8h f3 = *reinterpret_cast<const v8h*>(hb + 192);                          \
        v4f c00 = bh[0][0], c01 = bh[0][1];                                        \
        v4f c10 = bh[1][0], c11 = bh[1][1];                                        \
        v4f c20 = bh[2][0], c21 = bh[2][1];                                        \
        MM(c00, 0, 0, 0, f0); MM(c01, 0, 1, 0, f0);                                \
        MM(c10, 1, 0, 0, f0); MM(c11, 1, 1, 0, f0);                                \
        MM(c20, 2, 0, 0, f0); MM(c21, 2, 1, 0, f0);                                \
        MM(c00, 0, 0, 1, f1); MM(c01, 0, 1, 1, f1);                                \
        MM(c10, 1, 0, 1, f1); MM(c11, 1, 1, 1, f1);                                \
        MM(c20, 2, 0, 1, f1); MM(c21, 2, 1, 1, f1);                                \
        MM(c00, 0, 0, 2, f2); MM(c01, 0, 1, 2, f2);                                \
        MM(c10, 1, 0, 2, f2); MM(c11, 1, 1, 2, f2);                                \
        MM(c20, 2, 0, 2, f2); MM(c21, 2, 1, 2, f2);                                \
        MM(c00, 0, 0, 3, f3); MM(c01, 0, 1, 3, f3);                                \
        MM(c10, 1, 0, 3, f3); MM(c11, 1, 1, 3, f3);                                \
        MM(c20, 2, 0, 3, f3); MM(c21, 2, 1, 3, f3);                                \
        float ghr = t2s ? sel4(c01, sel) : sel4(c00, sel);                         \
        float ghz = t2s ? sel4(c11, sel) : sel4(c10, sel);                         \
        float ghn = t2s ? sel4(c21, sel) : sel4(c20, sel);                         \
        float iR = (float)__builtin_bit_cast(_Float16, (unsigned short)(RZ & 0xffff)); \
        float iZ = (float)__builtin_bit_cast(_Float16, (unsigned short)(RZ >> 16));    \
        float iN = (float)NV;                                                      \
        float rr = sigm(iR + ghr);                                                 \
        float zz = sigm(iZ + ghz);                                                 \
        float nn = tanh_(fmaf(rr, ghn, iN));                                       \
        float hn = fmaf(zz, hprev - nn, nn);                                       \
        hprev = hn;                                                                \
        if (active) {                                                              \
            h_lds[(P) ^ 1][j] = (_Float16)hn;                                      \
            *outp = hn;                                                            \
        }                                                                          \
        outp += OW;                                                                \
        if (DO_PF) {                                                               \
            RZ = *reinterpret_cast<const unsigned int*>(PPTR + off_rz);            \
            NV = *reinterpret_cast<const _Float16*>(PPTR + off_nv);                \
            PPTR += 1536;                                                          \
        }                                                                          \
        asm volatile("s_waitcnt lgkmcnt(0)" ::: "memory");                         \
        __builtin_amdgcn_s_barrier();                                              \
        __builtin_amdgcn_sched_barrier(0);                                         \
    }

    for (int t = 0; t < NT - 2; t += 2) {
        STEP(0, rz0, nv0, pEb, 1)
        STEP(1, rz1, nv1, pOb, 1)
    }
    // epilogue t = 998, 999 (no prefetch)
    STEP(0, rz0, nv0, pEb, 0)
    STEP(1, rz1, nv1, pOb, 0)
#undef STEP
#undef MM
}

extern "C" void kernel_launch(void* const* d_in, const int* in_sizes, int n_in,
                              void* d_out, int out_size, void* d_ws, size_t ws_size,
                              hipStream_t stream) {
    const float* x    = (const float*)d_in[0];
    const float* w_ih = (const float*)d_in[1];
    const float* w_hh = (const float*)d_in[2];
    const float* b_ih = (const float*)d_in[3];
    const float* b_hh = (const float*)d_in[4];
    float* out = (float*)d_out;
    _Float16* gi_ws = (_Float16*)d_ws;   // 98.304 MB, layout above

    dim3 g1(3, NB * 8, NG);
    gi_gemm4<<<g1, 256, 0, stream>>>(x, w_ih, b_ih, gi_ws);
    gru_recE<<<NB * NG, 256, 0, stream>>>(gi_ws, w_hh, b_hh, out);
}